// Round 1
// baseline (3173.361 us; speedup 1.0000x reference)
//
#include <hip/hip_runtime.h>
#include <hip/hip_bf16.h>
#include <cstdint>

// Problem constants (fixed by reference):
//   B=16, D=8, S=256, L=512, BD=B*D=128, M=B*D*S=32768, F=3L=1536
// d_out = [output: 16*2048*512] ++ [output_matrix_attn: 16*2048*2048], fp32.

#define SQ 256
#define LQ 512
#define FQ 1536
#define BDQ 128

// ---------------------------------------------------------------------------
// Kernel 1: QKV projection.  C[m][f] = sum_l X[m][l]*W[f][l] + bias[f]
// NT GEMM (both operands K-major rows). 128x128 block tile, BK=16,
// 256 threads, 8x8 micro-tile per thread, fp32 vector ALU.
// ---------------------------------------------------------------------------
__global__ __launch_bounds__(256) void qkv_gemm(const float* __restrict__ X,
                                                const float* __restrict__ W,
                                                const float* __restrict__ bias,
                                                float* __restrict__ C) {
    __shared__ float sX[16][132];  // [k][m], +4 pad keeps float4 align & shifts banks
    __shared__ float sW[16][132];  // [k][f]
    const int tid = threadIdx.x;
    const int m0 = blockIdx.y * 128;
    const int f0 = blockIdx.x * 128;
    const int tx = tid & 15;       // m-direction
    const int ty = tid >> 4;       // f-direction
    const int mi = tx * 8;
    const int fi = ty * 8;

    float acc[8][8] = {};

    for (int l0 = 0; l0 < LQ; l0 += 16) {
        // Stage: 128 rows x 16 k each for X and W; 512 float4 per operand,
        // 256 threads -> 2 float4 each, transposed into [k][row].
#pragma unroll
        for (int u = 0; u < 2; ++u) {
            const int idx = tid + u * 256;      // 0..511
            const int row = idx >> 2;           // 0..127
            const int kg  = idx & 3;            // 0..3
            const float4 xv = *(const float4*)&X[(size_t)(m0 + row) * LQ + l0 + kg * 4];
            sX[kg * 4 + 0][row] = xv.x;
            sX[kg * 4 + 1][row] = xv.y;
            sX[kg * 4 + 2][row] = xv.z;
            sX[kg * 4 + 3][row] = xv.w;
            const float4 wv = *(const float4*)&W[(size_t)(f0 + row) * LQ + l0 + kg * 4];
            sW[kg * 4 + 0][row] = wv.x;
            sW[kg * 4 + 1][row] = wv.y;
            sW[kg * 4 + 2][row] = wv.z;
            sW[kg * 4 + 3][row] = wv.w;
        }
        __syncthreads();

#pragma unroll
        for (int kk = 0; kk < 16; ++kk) {
            float a[8], b[8];
            *(float4*)&a[0] = *(const float4*)&sX[kk][mi];
            *(float4*)&a[4] = *(const float4*)&sX[kk][mi + 4];
            *(float4*)&b[0] = *(const float4*)&sW[kk][fi];
            *(float4*)&b[4] = *(const float4*)&sW[kk][fi + 4];
#pragma unroll
            for (int i = 0; i < 8; ++i)
#pragma unroll
                for (int j = 0; j < 8; ++j)
                    acc[i][j] += a[i] * b[j];
        }
        __syncthreads();
    }

    // Epilogue: + bias, fp32 store.
#pragma unroll
    for (int j = 0; j < 8; j += 4) {
        const float4 bv = *(const float4*)&bias[f0 + fi + j];
#pragma unroll
        for (int i = 0; i < 8; ++i) {
            const int m = m0 + mi + i;
            float4 o;
            o.x = acc[i][j + 0] + bv.x;
            o.y = acc[i][j + 1] + bv.y;
            o.z = acc[i][j + 2] + bv.z;
            o.w = acc[i][j + 3] + bv.w;
            *(float4*)&C[(size_t)m * FQ + f0 + fi + j] = o;
        }
    }
}

// ---------------------------------------------------------------------------
// Kernel 2: per-(b,d) attention. One block = (bd, 16-row q-tile).
// scores = qk^T/sqrt(L) -> softmax -> post-softmax mask -> write attn into
// the block-diagonal of output_matrix_attn -> out = attn @ v.
// ---------------------------------------------------------------------------
__global__ __launch_bounds__(256) void attn_kernel(const float* __restrict__ qkv,
                                                   const int* __restrict__ n_ptr,
                                                   float* __restrict__ out,
                                                   float* __restrict__ outmat) {
    constexpr int RT = 16;
    __shared__ float sQ[RT][516];   // pad 512->516: 4-bank shift between rows
    __shared__ float sS[RT][260];   // pad 256->260
    __shared__ float sRed[RT][16];
    __shared__ float rowMax[RT];
    __shared__ float rowSum[RT];

    const int tid = threadIdx.x;
    const int bd  = blockIdx.x;          // 0..127  (bd = b*8 + d)
    const int rt  = blockIdx.y;          // 0..15
    const int r0  = rt * RT;
    const int n   = *n_ptr;
    const size_t base = (size_t)bd * SQ * FQ;   // qkv rows for this (b,d)

    // ---- load Q tile into LDS (16 rows x 512) ----
    for (int i = tid; i < RT * 128; i += 256) {
        const int r  = i >> 7;
        const int lv = i & 127;
        *(float4*)&sQ[r][lv * 4] =
            *(const float4*)&qkv[base + (size_t)(r0 + r) * FQ + lv * 4];
    }
    __syncthreads();

    const int tx = tid & 15;   // column-group
    const int ty = tid >> 4;   // row within tile (0..15)

    // ---- scores: row ty, t in [tx*16, tx*16+16) ----
    float sc[16];
#pragma unroll 4
    for (int j = 0; j < 16; ++j) {
        const int t = tx * 16 + j;
        const float* krow = &qkv[base + (size_t)t * FQ + LQ];
        float a0 = 0.f, a1 = 0.f, a2 = 0.f, a3 = 0.f;
        for (int l = 0; l < LQ; l += 4) {
            const float4 kv = *(const float4*)&krow[l];
            const float4 qv = *(const float4*)&sQ[ty][l];
            a0 += qv.x * kv.x;
            a1 += qv.y * kv.y;
            a2 += qv.z * kv.z;
            a3 += qv.w * kv.w;
        }
        sc[j] = (a0 + a1 + a2 + a3) * 0.044194173824159216f;  // 1/sqrt(512)
    }

    // ---- softmax over t (stable) ----
    float lmax = -1e30f;
#pragma unroll
    for (int j = 0; j < 16; ++j) lmax = fmaxf(lmax, sc[j]);
    sRed[ty][tx] = lmax;
    __syncthreads();
    if (tid < RT) {
        float m = sRed[tid][0];
#pragma unroll
        for (int k = 1; k < 16; ++k) m = fmaxf(m, sRed[tid][k]);
        rowMax[tid] = m;
    }
    __syncthreads();
    const float rmax = rowMax[ty];
    float lsum = 0.f;
#pragma unroll
    for (int j = 0; j < 16; ++j) {
        sc[j] = __expf(sc[j] - rmax);
        lsum += sc[j];
    }
    sRed[ty][tx] = lsum;
    __syncthreads();
    if (tid < RT) {
        float s = 0.f;
#pragma unroll
        for (int k = 0; k < 16; ++k) s += sRed[tid][k];
        rowSum[tid] = s;
    }
    __syncthreads();
    const float inv = 1.0f / rowSum[ty];
    const int i_glob = r0 + ty;

    // ---- normalize + post-softmax mask; stash in sS and write to outmat ----
    float av[16];
#pragma unroll
    for (int j = 0; j < 16; ++j) {
        const int t = tx * 16 + j;
        float a = sc[j] * inv;
        const int d = (i_glob > t) ? (i_glob - t) : (t - i_glob);
        int ov = 512 - d * n;
        if (ov < 0) ov = 0;
        const bool mask = (d == 0) || ((2 * ov >= 512) && (ov < 512));
        if (mask) a = 0.f;
        av[j] = a;
        sS[ty][t] = a;
    }
    {
        const int b  = bd >> 3;
        const int dd = bd & 7;
        float* dst = &outmat[(size_t)b * 4194304 +
                             (size_t)(dd * 256 + i_glob) * 2048 + dd * 256 + tx * 16];
#pragma unroll
        for (int j = 0; j < 16; j += 4)
            *(float4*)&dst[j] = make_float4(av[j], av[j + 1], av[j + 2], av[j + 3]);
    }
    __syncthreads();

    // ---- PV: out[ty][l] ; each thread owns l = (tx + 16c)*4 .. +3, c<8 ----
    float4 acc[8];
#pragma unroll
    for (int c = 0; c < 8; ++c) acc[c] = make_float4(0.f, 0.f, 0.f, 0.f);
    for (int t = 0; t < SQ; ++t) {
        const float a = sS[ty][t];
        const float* vrow = &qkv[base + (size_t)t * FQ + 2 * LQ];
#pragma unroll
        for (int c = 0; c < 8; ++c) {
            const float4 vv = *(const float4*)&vrow[(tx + 16 * c) * 4];
            acc[c].x += a * vv.x;
            acc[c].y += a * vv.y;
            acc[c].z += a * vv.z;
            acc[c].w += a * vv.w;
        }
    }
#pragma unroll
    for (int c = 0; c < 8; ++c) {
        *(float4*)&out[((size_t)bd * SQ + i_glob) * LQ + (tx + 16 * c) * 4] = acc[c];
    }
}

// ---------------------------------------------------------------------------
extern "C" void kernel_launch(void* const* d_in, const int* in_sizes, int n_in,
                              void* d_out, int out_size, void* d_ws, size_t ws_size,
                              hipStream_t stream) {
    (void)in_sizes; (void)n_in; (void)out_size; (void)ws_size;
    const float* x     = (const float*)d_in[0];   // [16,8,256,512]
    const float* Wqkv  = (const float*)d_in[1];   // [1536,512]
    const float* bqkv  = (const float*)d_in[2];   // [1536]
    const int*   n_ptr = (const int*)d_in[3];     // scalar

    float* out    = (float*)d_out;                // [16*2048*512]
    float* outmat = out + (size_t)16 * 2048 * 512;  // [16*2048*2048]
    float* qkv    = (float*)d_ws;                 // [32768][1536] fp32 = 201.3 MB

    // Zero the attention matrix region; attn kernel fills the block diagonal.
    hipMemsetAsync(outmat, 0, (size_t)16 * 2048 * 2048 * sizeof(float), stream);

    dim3 g1(FQ / 128, 32768 / 128);   // (12, 256)
    qkv_gemm<<<g1, 256, 0, stream>>>(x, Wqkv, bqkv, qkv);

    dim3 g2(BDQ, SQ / 16);            // (128, 16)
    attn_kernel<<<g2, 256, 0, stream>>>(qkv, n_ptr, out, outmat);
}

// Round 2
// 2184.915 us; speedup vs baseline: 1.4524x; 1.4524x over previous
//
#include <hip/hip_runtime.h>
#include <hip/hip_bf16.h>
#include <cstdint>

// Problem constants (fixed by reference):
//   B=16, D=8, S=256, L=512, BD=B*D=128, M=B*D*S=32768, F=3L=1536
// d_out = [output: 16*2048*512] ++ [output_matrix_attn: 16*2048*2048], fp32.

#define SQ 256
#define LQ 512
#define FQ 1536
#define BDQ 128

// ---------------------------------------------------------------------------
// Kernel 1: QKV projection.  C[m][f] = sum_l X[m][l]*W[f][l] + bias[f]
// NT GEMM (both operands K-major rows). 128x128 block tile, BK=16,
// 256 threads, 8x8 micro-tile per thread, fp32 vector ALU.
// ---------------------------------------------------------------------------
__global__ __launch_bounds__(256) void qkv_gemm(const float* __restrict__ X,
                                                const float* __restrict__ W,
                                                const float* __restrict__ bias,
                                                float* __restrict__ C) {
    __shared__ float sX[16][132];  // [k][m]
    __shared__ float sW[16][132];  // [k][f]
    const int tid = threadIdx.x;
    const int m0 = blockIdx.y * 128;
    const int f0 = blockIdx.x * 128;
    const int tx = tid & 15;       // m-direction
    const int ty = tid >> 4;       // f-direction
    const int mi = tx * 8;
    const int fi = ty * 8;

    float acc[8][8] = {};

    for (int l0 = 0; l0 < LQ; l0 += 16) {
#pragma unroll
        for (int u = 0; u < 2; ++u) {
            const int idx = tid + u * 256;      // 0..511
            const int row = idx >> 2;           // 0..127
            const int kg  = idx & 3;            // 0..3
            const float4 xv = *(const float4*)&X[(size_t)(m0 + row) * LQ + l0 + kg * 4];
            sX[kg * 4 + 0][row] = xv.x;
            sX[kg * 4 + 1][row] = xv.y;
            sX[kg * 4 + 2][row] = xv.z;
            sX[kg * 4 + 3][row] = xv.w;
            const float4 wv = *(const float4*)&W[(size_t)(f0 + row) * LQ + l0 + kg * 4];
            sW[kg * 4 + 0][row] = wv.x;
            sW[kg * 4 + 1][row] = wv.y;
            sW[kg * 4 + 2][row] = wv.z;
            sW[kg * 4 + 3][row] = wv.w;
        }
        __syncthreads();

#pragma unroll
        for (int kk = 0; kk < 16; ++kk) {
            float a[8], b[8];
            *(float4*)&a[0] = *(const float4*)&sX[kk][mi];
            *(float4*)&a[4] = *(const float4*)&sX[kk][mi + 4];
            *(float4*)&b[0] = *(const float4*)&sW[kk][fi];
            *(float4*)&b[4] = *(const float4*)&sW[kk][fi + 4];
#pragma unroll
            for (int i = 0; i < 8; ++i)
#pragma unroll
                for (int j = 0; j < 8; ++j)
                    acc[i][j] += a[i] * b[j];
        }
        __syncthreads();
    }

#pragma unroll
    for (int j = 0; j < 8; j += 4) {
        const float4 bv = *(const float4*)&bias[f0 + fi + j];
#pragma unroll
        for (int i = 0; i < 8; ++i) {
            const int m = m0 + mi + i;
            float4 o;
            o.x = acc[i][j + 0] + bv.x;
            o.y = acc[i][j + 1] + bv.y;
            o.z = acc[i][j + 2] + bv.z;
            o.w = acc[i][j + 3] + bv.w;
            *(float4*)&C[(size_t)m * FQ + f0 + fi + j] = o;
        }
    }
}

// ---------------------------------------------------------------------------
// Kernel 2: per-(b,d) attention, LDS-tiled GEMM version.
// Block = (q-tile of 32 rows, bd). 256 threads as 8(tm) x 32(tn),
// micro-tile 4 rows x 8 cols.
// Phase 1: scores[32x256] = Q K^T / sqrt(L), K-chunks staged in LDS.
// Phase 2: softmax + post-softmax mask; attn -> outmat + LDS.
// Phase 3: out[32x512] = attn @ V, V-chunks staged in LDS.
// ---------------------------------------------------------------------------
__global__ __launch_bounds__(256) void attn_kernel(const float* __restrict__ qkv,
                                                   const int* __restrict__ n_ptr,
                                                   float* __restrict__ out,
                                                   float* __restrict__ outmat) {
    __shared__ union {
        struct {
            float sQt[32][40];    // [l][m], row=160B (16B aligned for float4)
            float sKt[32][260];   // [l][t], row=1040B (16B aligned)
        } p1;
        struct {
            float sV[32][264];    // [t][n-chunk 256], row=1056B (16B aligned)
        } p3;
    } sm;
    __shared__ float sS[32][260];     // attn [m][t]
    __shared__ float sRed[32][33];
    __shared__ float rowStat[32];

    const int tid = threadIdx.x;
    const int r0  = blockIdx.x * 32;     // q-row tile
    const int bd  = blockIdx.y;          // 0..127
    const int n   = *n_ptr;
    const size_t base = (size_t)bd * SQ * FQ;

    const int tn = tid & 31;   // t / n direction
    const int tm = tid >> 5;   // m direction (8 groups of 4 rows)

    const int srow = tid >> 3; // staging: row 0..31
    const int slg  = tid & 7;  // staging: 16B group 0..7

    float acc[4][8] = {};

    // ================= Phase 1: scores =================
#pragma unroll 1
    for (int l0 = 0; l0 < LQ; l0 += 32) {
        {   // Q chunk: 32 rows x 32 l, transposed
            const float4 v = *(const float4*)&qkv[base + (size_t)(r0 + srow) * FQ + l0 + slg * 4];
            sm.p1.sQt[slg * 4 + 0][srow] = v.x;
            sm.p1.sQt[slg * 4 + 1][srow] = v.y;
            sm.p1.sQt[slg * 4 + 2][srow] = v.z;
            sm.p1.sQt[slg * 4 + 3][srow] = v.w;
        }
#pragma unroll
        for (int u = 0; u < 8; ++u) {   // K chunk: 256 rows x 32 l, transposed
            const int idx = tid + u * 256;
            const int row = idx >> 3;
            const int lg  = idx & 7;
            const float4 v = *(const float4*)&qkv[base + (size_t)row * FQ + LQ + l0 + lg * 4];
            sm.p1.sKt[lg * 4 + 0][row] = v.x;
            sm.p1.sKt[lg * 4 + 1][row] = v.y;
            sm.p1.sKt[lg * 4 + 2][row] = v.z;
            sm.p1.sKt[lg * 4 + 3][row] = v.w;
        }
        __syncthreads();

#pragma unroll
        for (int kk = 0; kk < 32; ++kk) {
            const float4 a4 = *(const float4*)&sm.p1.sQt[kk][tm * 4];
            const float4 b0 = *(const float4*)&sm.p1.sKt[kk][tn * 8];
            const float4 b1 = *(const float4*)&sm.p1.sKt[kk][tn * 8 + 4];
            const float a_[4] = {a4.x, a4.y, a4.z, a4.w};
            const float b_[8] = {b0.x, b0.y, b0.z, b0.w, b1.x, b1.y, b1.z, b1.w};
#pragma unroll
            for (int i = 0; i < 4; ++i)
#pragma unroll
                for (int j = 0; j < 8; ++j)
                    acc[i][j] += a_[i] * b_[j];
        }
        __syncthreads();
    }

    // ================= Phase 2: softmax + mask =================
    const float scale = 0.044194173824159216f;  // 1/sqrt(512)
#pragma unroll
    for (int i = 0; i < 4; ++i)
#pragma unroll
        for (int j = 0; j < 8; ++j) acc[i][j] *= scale;

    // row max
#pragma unroll
    for (int i = 0; i < 4; ++i) {
        float m = acc[i][0];
#pragma unroll
        for (int j = 1; j < 8; ++j) m = fmaxf(m, acc[i][j]);
        sRed[tm * 4 + i][tn] = m;
    }
    __syncthreads();
    if (tid < 32) {
        float m = sRed[tid][0];
#pragma unroll
        for (int k = 1; k < 32; ++k) m = fmaxf(m, sRed[tid][k]);
        rowStat[tid] = m;
    }
    __syncthreads();
    // exp + row sum
#pragma unroll
    for (int i = 0; i < 4; ++i) {
        const float rmax = rowStat[tm * 4 + i];
        float s = 0.f;
#pragma unroll
        for (int j = 0; j < 8; ++j) {
            acc[i][j] = __expf(acc[i][j] - rmax);
            s += acc[i][j];
        }
        sRed[tm * 4 + i][tn] = s;
    }
    __syncthreads();
    if (tid < 32) {
        float s = 0.f;
#pragma unroll
        for (int k = 0; k < 32; ++k) s += sRed[tid][k];
        rowStat[tid] = s;
    }
    __syncthreads();

    const int b_ = bd >> 3;
    const int dd = bd & 7;
#pragma unroll
    for (int i = 0; i < 4; ++i) {
        const int r  = tm * 4 + i;
        const int ig = r0 + r;
        const float inv = 1.0f / rowStat[r];
        float av[8];
#pragma unroll
        for (int j = 0; j < 8; ++j) {
            const int t = tn * 8 + j;
            float a = acc[i][j] * inv;
            const int d = (ig > t) ? (ig - t) : (t - ig);
            int ov = 512 - d * n;
            if (ov < 0) ov = 0;
            if (d == 0 || ((2 * ov >= 512) && (ov < 512))) a = 0.f;
            av[j] = a;
        }
        *(float4*)&sS[r][tn * 8]     = make_float4(av[0], av[1], av[2], av[3]);
        *(float4*)&sS[r][tn * 8 + 4] = make_float4(av[4], av[5], av[6], av[7]);
        float* dst = &outmat[(size_t)b_ * 4194304 +
                             (size_t)(dd * 256 + ig) * 2048 + dd * 256 + tn * 8];
        *(float4*)&dst[0] = make_float4(av[0], av[1], av[2], av[3]);
        *(float4*)&dst[4] = make_float4(av[4], av[5], av[6], av[7]);
    }
    __syncthreads();

    // ================= Phase 3: out = attn @ V =================
#pragma unroll 1
    for (int n0 = 0; n0 < LQ; n0 += 256) {
        float o[4][8] = {};
#pragma unroll 1
        for (int t0 = 0; t0 < SQ; t0 += 32) {
            __syncthreads();
#pragma unroll
            for (int u = 0; u < 8; ++u) {   // V chunk: 32 rows x 256 cols
                const int idx = tid + u * 256;
                const int row = idx >> 6;   // 0..31
                const int cg  = idx & 63;   // 0..63
                *(float4*)&sm.p3.sV[row][cg * 4] =
                    *(const float4*)&qkv[base + (size_t)(t0 + row) * FQ + 2 * LQ + n0 + cg * 4];
            }
            __syncthreads();
#pragma unroll
            for (int kk = 0; kk < 32; ++kk) {
                const float a0 = sS[tm * 4 + 0][t0 + kk];
                const float a1 = sS[tm * 4 + 1][t0 + kk];
                const float a2 = sS[tm * 4 + 2][t0 + kk];
                const float a3 = sS[tm * 4 + 3][t0 + kk];
                const float4 b0 = *(const float4*)&sm.p3.sV[kk][tn * 8];
                const float4 b1 = *(const float4*)&sm.p3.sV[kk][tn * 8 + 4];
                const float a_[4] = {a0, a1, a2, a3};
                const float b_[8] = {b0.x, b0.y, b0.z, b0.w, b1.x, b1.y, b1.z, b1.w};
#pragma unroll
                for (int i = 0; i < 4; ++i)
#pragma unroll
                    for (int j = 0; j < 8; ++j)
                        o[i][j] += a_[i] * b_[j];
            }
        }
#pragma unroll
        for (int i = 0; i < 4; ++i) {
            const int ig = r0 + tm * 4 + i;
            *(float4*)&out[((size_t)bd * SQ + ig) * LQ + n0 + tn * 8] =
                make_float4(o[i][0], o[i][1], o[i][2], o[i][3]);
            *(float4*)&out[((size_t)bd * SQ + ig) * LQ + n0 + tn * 8 + 4] =
                make_float4(o[i][4], o[i][5], o[i][6], o[i][7]);
        }
    }
}

// ---------------------------------------------------------------------------
extern "C" void kernel_launch(void* const* d_in, const int* in_sizes, int n_in,
                              void* d_out, int out_size, void* d_ws, size_t ws_size,
                              hipStream_t stream) {
    (void)in_sizes; (void)n_in; (void)out_size; (void)ws_size;
    const float* x     = (const float*)d_in[0];   // [16,8,256,512]
    const float* Wqkv  = (const float*)d_in[1];   // [1536,512]
    const float* bqkv  = (const float*)d_in[2];   // [1536]
    const int*   n_ptr = (const int*)d_in[3];     // scalar

    float* out    = (float*)d_out;                  // [16*2048*512]
    float* outmat = out + (size_t)16 * 2048 * 512;  // [16*2048*2048]
    float* qkv    = (float*)d_ws;                   // [32768][1536] fp32

    // Zero the attention matrix region; attn kernel fills the block diagonal.
    hipMemsetAsync(outmat, 0, (size_t)16 * 2048 * 2048 * sizeof(float), stream);

    dim3 g1(FQ / 128, 32768 / 128);   // (12, 256)
    qkv_gemm<<<g1, 256, 0, stream>>>(x, Wqkv, bqkv, qkv);

    dim3 g2(SQ / 32, BDQ);            // (8, 128)
    attn_kernel<<<g2, 256, 0, stream>>>(qkv, n_ptr, out, outmat);
}

// Round 3
// 538.603 us; speedup vs baseline: 5.8918x; 4.0566x over previous
//
#include <hip/hip_runtime.h>
#include <hip/hip_bf16.h>
#include <cstdint>

// B=16, D=8, S=256, L=512, BD=128, M=32768, F=1536
// d_out = [output: 16*2048*512] ++ [output_matrix_attn: 16*2048*2048], fp32.

typedef unsigned short u16;
typedef short bf16x8 __attribute__((ext_vector_type(8)));   // 8 bf16 (4 VGPRs)
typedef float f32x4 __attribute__((ext_vector_type(4)));    // MFMA accumulator

__device__ __forceinline__ u16 f2bf(float f) {
    union { float f; unsigned int u; } v; v.f = f;
    unsigned int r = v.u + 0x7FFF + ((v.u >> 16) & 1);      // round-to-nearest-even
    return (u16)(r >> 16);
}

// async global->LDS, 16B per lane; LDS dest = wave-uniform base + lane*16
__device__ __forceinline__ void gload16(const u16* g, u16* l) {
    __builtin_amdgcn_global_load_lds(
        (const __attribute__((address_space(1))) unsigned int*)g,
        (__attribute__((address_space(3))) unsigned int*)l, 16, 0, 0);
}

__device__ __forceinline__ f32x4 mfma16(bf16x8 a, bf16x8 b, f32x4 c) {
    return __builtin_amdgcn_mfma_f32_16x16x32_bf16(a, b, c, 0, 0, 0);
}

// ---------------------------------------------------------------------------
// Kernel 0: fp32 -> bf16 cast of x and Wqkv (8 elems/thread).
// ---------------------------------------------------------------------------
__global__ __launch_bounds__(256) void cast_bf16(const float* __restrict__ x,
                                                 const float* __restrict__ w,
                                                 u16* __restrict__ xb,
                                                 u16* __restrict__ wb) {
    const size_t NX = 16777216 / 8, NW = 786432 / 8;
    size_t i = (size_t)blockIdx.x * 256 + threadIdx.x;
    const float* src; u16* dst; size_t e;
    if (i < NX)            { src = x; dst = xb; e = i; }
    else if (i < NX + NW)  { src = w; dst = wb; e = i - NX; }
    else return;
    const float4 a = *(const float4*)&src[e * 8];
    const float4 b = *(const float4*)&src[e * 8 + 4];
    u16 o[8] = { f2bf(a.x), f2bf(a.y), f2bf(a.z), f2bf(a.w),
                 f2bf(b.x), f2bf(b.y), f2bf(b.z), f2bf(b.w) };
    *(uint4*)&dst[e * 8] = *(const uint4*)o;
}

// ---------------------------------------------------------------------------
// Kernel 1: QKV projection, bf16 MFMA.  C[m][f] = sum_l X[m][l] W[f][l] + b[f]
// Block 128m x 256f, BK=32, 256 thr (4 waves), wave = 64m x 128f
//   = 4 mtiles x 8 ftiles of 16x16, k-steps of 32.
// LDS fragment-major: per (tile,kchunk) 64 chunks of 16B ordered [h4][row16].
// f < 1024 -> qk[m][f] bf16 ; f >= 1024 -> vt[bd][n][t] bf16 (transposed).
// ---------------------------------------------------------------------------
__global__ __launch_bounds__(256, 2) void qkv_gemm(const u16* __restrict__ xb,
                                                   const u16* __restrict__ wb,
                                                   const float* __restrict__ bias,
                                                   u16* __restrict__ qk,
                                                   u16* __restrict__ vt) {
    __shared__ __align__(16) u16 sA[8 * 512];    // 8 m-tiles
    __shared__ __align__(16) u16 sB[16 * 512];   // 16 f-tiles
    const int tid = threadIdx.x, lane = tid & 63, w = tid >> 6;
    const int lr = lane & 15, lh = lane >> 4;
    const int f0 = blockIdx.x * 256, m0 = blockIdx.y * 128;
    const int wm = w & 1, wf = w >> 1;

    f32x4 acc[4][8];
#pragma unroll
    for (int i = 0; i < 4; ++i)
#pragma unroll
        for (int j = 0; j < 8; ++j) acc[i][j] = (f32x4){0.f, 0.f, 0.f, 0.f};

    for (int k0 = 0; k0 < 512; k0 += 32) {
#pragma unroll
        for (int i = 0; i < 6; ++i) {            // 24 staging jobs, 6 per wave
            const int j = w * 6 + i;
            if (j < 8) {
                gload16(xb + (size_t)(m0 + j * 16 + lr) * 512 + k0 + lh * 8,
                        &sA[j * 512]);
            } else {
                const int jb = j - 8;
                gload16(wb + (size_t)(f0 + jb * 16 + lr) * 512 + k0 + lh * 8,
                        &sB[jb * 512]);
            }
        }
        __syncthreads();
        bf16x8 af[4], bf[8];
#pragma unroll
        for (int mt = 0; mt < 4; ++mt)
            af[mt] = *(const bf16x8*)&sA[(wm * 4 + mt) * 512 + lane * 8];
#pragma unroll
        for (int ft = 0; ft < 8; ++ft)
            bf[ft] = *(const bf16x8*)&sB[(wf * 8 + ft) * 512 + lane * 8];
#pragma unroll
        for (int mt = 0; mt < 4; ++mt)
#pragma unroll
            for (int ft = 0; ft < 8; ++ft)
                acc[mt][ft] = mfma16(af[mt], bf[ft], acc[mt][ft]);
        __syncthreads();
    }

    // Epilogue. C layout: col = lane&15, row = (lane>>4)*4 + reg.
    const bool isV = (f0 >= 1024);
#pragma unroll
    for (int ft = 0; ft < 8; ++ft) {
        const int f = f0 + wf * 128 + ft * 16 + lr;
        const float bv = bias[f];
#pragma unroll
        for (int mt = 0; mt < 4; ++mt) {
            const int mbase = m0 + wm * 64 + mt * 16 + lh * 4;
            const f32x4 a = acc[mt][ft];
            if (!isV) {
#pragma unroll
                for (int r = 0; r < 4; ++r)
                    qk[(size_t)(mbase + r) * 1024 + f] = f2bf(a[r] + bv);
            } else {
                const int nn = f - 1024;
                const int bd = mbase >> 8, t = mbase & 255;   // t % 4 == 0
                ushort4 pk;
                pk.x = f2bf(a[0] + bv); pk.y = f2bf(a[1] + bv);
                pk.z = f2bf(a[2] + bv); pk.w = f2bf(a[3] + bv);
                *(ushort4*)&vt[(size_t)bd * 131072 + (size_t)nn * 256 + t] = pk;
            }
        }
    }
}

// ---------------------------------------------------------------------------
// Kernel 2: attention, bf16 MFMA. Block = (128 q-rows, bd), grid (2,128).
// Phase 1: S = Q K^T (frag-major staged from qk).
// Phase 2: softmax + post-softmax mask; attn -> outmat + sP (frag-major bf16).
// Phase 3: out = P V via sP x staged V^T tiles.
// ---------------------------------------------------------------------------
#define HS 136                 // sP h-stride (elems): 272B, bank shift 4
#define MT 552                 // sP mtile-stride: 4*HS + 8
#define KS 4432                // sP kstep-stride: 8*MT + 16
__global__ __launch_bounds__(256, 1) void attn_kernel(const u16* __restrict__ qk,
                                                      const u16* __restrict__ vt,
                                                      const int* __restrict__ n_ptr,
                                                      float* __restrict__ out,
                                                      float* __restrict__ outmat) {
    __shared__ __align__(16) u16 sQ[8 * 512];
    __shared__ __align__(16) u16 sK[16 * 512];      // reused for V^T in phase 3
    __shared__ __align__(16) u16 sP[8 * KS];        // 70912 B
    __shared__ float sStat[128][2];

    const int tid = threadIdx.x, lane = tid & 63, w = tid >> 6;
    const int lr = lane & 15, lh = lane >> 4;
    const int r0 = blockIdx.x * 128, bd = blockIdx.y;
    const int n = *n_ptr;
    const int wm = w & 1, wt = w >> 1;
    const size_t qbase = (size_t)bd * 256 * 1024;

    f32x4 acc[4][8];
#pragma unroll
    for (int i = 0; i < 4; ++i)
#pragma unroll
        for (int j = 0; j < 8; ++j) acc[i][j] = (f32x4){0.f, 0.f, 0.f, 0.f};

    // ---------------- Phase 1: scores ----------------
    for (int k0 = 0; k0 < 512; k0 += 32) {
#pragma unroll
        for (int i = 0; i < 6; ++i) {
            const int j = w * 6 + i;
            if (j < 8) {        // Q tiles: rows r0.., cols k0..
                gload16(qk + qbase + (size_t)(r0 + j * 16 + lr) * 1024 + k0 + lh * 8,
                        &sQ[j * 512]);
            } else {            // K tiles: rows t.., cols 512+k0..
                const int jb = j - 8;
                gload16(qk + qbase + (size_t)(jb * 16 + lr) * 1024 + 512 + k0 + lh * 8,
                        &sK[jb * 512]);
            }
        }
        __syncthreads();
        bf16x8 af[4], bf[8];
#pragma unroll
        for (int mt = 0; mt < 4; ++mt)
            af[mt] = *(const bf16x8*)&sQ[(wm * 4 + mt) * 512 + lane * 8];
#pragma unroll
        for (int jt = 0; jt < 8; ++jt)
            bf[jt] = *(const bf16x8*)&sK[(wt * 8 + jt) * 512 + lane * 8];
#pragma unroll
        for (int mt = 0; mt < 4; ++mt)
#pragma unroll
            for (int jt = 0; jt < 8; ++jt)
                acc[mt][jt] = mfma16(af[mt], bf[jt], acc[mt][jt]);
        __syncthreads();
    }

    // ---------------- Phase 2: softmax + mask ----------------
    const float scale = 0.044194173824159216f;   // 1/sqrt(512)
#pragma unroll
    for (int i = 0; i < 4; ++i)
#pragma unroll
        for (int j = 0; j < 8; ++j) acc[i][j] *= scale;

    float rmax[4][4], rinv[4][4];
#pragma unroll
    for (int i = 0; i < 4; ++i)
#pragma unroll
        for (int r = 0; r < 4; ++r) {
            float v = -1e30f;
#pragma unroll
            for (int j = 0; j < 8; ++j) v = fmaxf(v, acc[i][j][r]);
            v = fmaxf(v, __shfl_xor(v, 1));
            v = fmaxf(v, __shfl_xor(v, 2));
            v = fmaxf(v, __shfl_xor(v, 4));
            v = fmaxf(v, __shfl_xor(v, 8));
            if (lr == 0) sStat[wm * 64 + i * 16 + lh * 4 + r][wt] = v;
        }
    __syncthreads();
#pragma unroll
    for (int i = 0; i < 4; ++i)
#pragma unroll
        for (int r = 0; r < 4; ++r) {
            const int m = wm * 64 + i * 16 + lh * 4 + r;
            rmax[i][r] = fmaxf(sStat[m][0], sStat[m][1]);
        }
    __syncthreads();
#pragma unroll
    for (int i = 0; i < 4; ++i)
#pragma unroll
        for (int r = 0; r < 4; ++r) {
            float s = 0.f;
#pragma unroll
            for (int j = 0; j < 8; ++j) {
                const float p = __expf(acc[i][j][r] - rmax[i][r]);
                acc[i][j][r] = p;
                s += p;
            }
            s += __shfl_xor(s, 1);
            s += __shfl_xor(s, 2);
            s += __shfl_xor(s, 4);
            s += __shfl_xor(s, 8);
            if (lr == 0) sStat[wm * 64 + i * 16 + lh * 4 + r][wt] = s;
        }
    __syncthreads();
#pragma unroll
    for (int i = 0; i < 4; ++i)
#pragma unroll
        for (int r = 0; r < 4; ++r) {
            const int m = wm * 64 + i * 16 + lh * 4 + r;
            rinv[i][r] = 1.0f / (sStat[m][0] + sStat[m][1]);
        }

    const int b_ = bd >> 3, dd = bd & 7;
#pragma unroll
    for (int i = 0; i < 4; ++i)
#pragma unroll
        for (int r = 0; r < 4; ++r) {
            const int m_loc = wm * 64 + i * 16 + lh * 4 + r;
            const int ig = r0 + m_loc;
            float* orow = &outmat[(size_t)b_ * 4194304 +
                                  (size_t)(dd * 256 + ig) * 2048 + dd * 256];
#pragma unroll
            for (int j = 0; j < 8; ++j) {
                const int t = wt * 128 + j * 16 + lr;
                float a = acc[i][j][r] * rinv[i][r];
                const int d = (ig > t) ? (ig - t) : (t - ig);
                int ov = 512 - d * n; if (ov < 0) ov = 0;
                if (d == 0 || ((2 * ov >= 512) && (ov < 512))) a = 0.f;
                orow[t] = a;
                sP[(t >> 5) * KS + (m_loc >> 4) * MT + ((t >> 3) & 3) * HS +
                   (m_loc & 15) * 8 + (t & 7)] = f2bf(a);
            }
        }
    __syncthreads();

    // ---------------- Phase 3: out = P V ----------------
    const int wn = wt;
#pragma unroll 1
    for (int nc = 0; nc < 2; ++nc) {
#pragma unroll
        for (int i = 0; i < 4; ++i)
#pragma unroll
            for (int j = 0; j < 8; ++j) acc[i][j] = (f32x4){0.f, 0.f, 0.f, 0.f};
#pragma unroll 1
        for (int t0 = 0; t0 < 256; t0 += 32) {
#pragma unroll
            for (int i = 0; i < 4; ++i) {        // 16 V^T tiles, 4 per wave
                const int nt = w * 4 + i;
                const int n_g = nc * 256 + nt * 16 + lr;
                gload16(vt + (size_t)bd * 131072 + (size_t)n_g * 256 + t0 + lh * 8,
                        &sK[nt * 512]);
            }
            __syncthreads();
            bf16x8 af[4], bf[8];
            const int kstep = t0 >> 5;
#pragma unroll
            for (int mt = 0; mt < 4; ++mt)
                af[mt] = *(const bf16x8*)&sP[kstep * KS + (wm * 4 + mt) * MT +
                                             lh * HS + lr * 8];
#pragma unroll
            for (int jt = 0; jt < 8; ++jt)
                bf[jt] = *(const bf16x8*)&sK[(wn * 8 + jt) * 512 + lane * 8];
#pragma unroll
            for (int mt = 0; mt < 4; ++mt)
#pragma unroll
                for (int jt = 0; jt < 8; ++jt)
                    acc[mt][jt] = mfma16(af[mt], bf[jt], acc[mt][jt]);
            __syncthreads();
        }
#pragma unroll
        for (int mt = 0; mt < 4; ++mt)
#pragma unroll
            for (int jt = 0; jt < 8; ++jt) {
                const int ng = nc * 256 + wn * 128 + jt * 16 + lr;
#pragma unroll
                for (int r = 0; r < 4; ++r) {
                    const int m_loc = wm * 64 + mt * 16 + lh * 4 + r;
                    out[((size_t)bd * 256 + r0 + m_loc) * 512 + ng] = acc[mt][jt][r];
                }
            }
    }
}

// ---------------------------------------------------------------------------
extern "C" void kernel_launch(void* const* d_in, const int* in_sizes, int n_in,
                              void* d_out, int out_size, void* d_ws, size_t ws_size,
                              hipStream_t stream) {
    (void)in_sizes; (void)n_in; (void)out_size; (void)ws_size;
    const float* x     = (const float*)d_in[0];   // [16,8,256,512]
    const float* Wqkv  = (const float*)d_in[1];   // [1536,512]
    const float* bqkv  = (const float*)d_in[2];   // [1536]
    const int*   n_ptr = (const int*)d_in[3];     // scalar

    float* out    = (float*)d_out;                  // [16*2048*512]
    float* outmat = out + (size_t)16 * 2048 * 512;  // [16*2048*2048]

    u16* xb = (u16*)d_ws;                 // 16,777,216 elems
    u16* wb = xb + 16777216;              //    786,432
    u16* qk = wb + 786432;                // 33,554,432 (32768 x 1024)
    u16* vt = qk + (size_t)33554432;      // 16,777,216 (128 x 512 x 256)

    hipMemsetAsync(outmat, 0, (size_t)16 * 2048 * 2048 * sizeof(float), stream);

    cast_bf16<<<8576, 256, 0, stream>>>(x, Wqkv, xb, wb);

    dim3 g1(6, 256);                      // F/256, M/128
    qkv_gemm<<<g1, 256, 0, stream>>>(xb, wb, bqkv, qk, vt);

    dim3 g2(2, 128);                      // q-tiles, bd
    attn_kernel<<<g2, 256, 0, stream>>>(qk, vt, n_ptr, out, outmat);
}

// Round 4
// 515.432 us; speedup vs baseline: 6.1567x; 1.0450x over previous
//
#include <hip/hip_runtime.h>
#include <hip/hip_bf16.h>
#include <cstdint>

// B=16, D=8, S=256, L=512, BD=128, M=32768, F=1536
// d_out = [output: 16*2048*512] ++ [output_matrix_attn: 16*2048*2048], fp32.
//
// Fragment-major layouts (16x16x32 bf16 MFMA, lane l, elem j):
//   A-type frag: X[m = tile*16 + (l&15)][k = kchunk*32 + (l>>4)*8 + j]
//   qb[bd][mtile16][kchunk16][512], kb[bd][ttile16][kchunk16][512],
//   vb[bd][ntile32][tchunk8][512]  (V stored transposed: lane&15 = n, elems = t)

typedef unsigned short u16;
typedef short bf16x8 __attribute__((ext_vector_type(8)));
typedef float f32x4 __attribute__((ext_vector_type(4)));

__device__ __forceinline__ u16 f2bf(float f) {
    union { float f; unsigned int u; } v; v.f = f;
    unsigned int r = v.u + 0x7FFF + ((v.u >> 16) & 1);
    return (u16)(r >> 16);
}

__device__ __forceinline__ void gload16(const u16* g, u16* l) {
    __builtin_amdgcn_global_load_lds(
        (const __attribute__((address_space(1))) unsigned int*)g,
        (__attribute__((address_space(3))) unsigned int*)l, 16, 0, 0);
}

__device__ __forceinline__ f32x4 mfma16(bf16x8 a, bf16x8 b, f32x4 c) {
    return __builtin_amdgcn_mfma_f32_16x16x32_bf16(a, b, c, 0, 0, 0);
}

// ---------------------------------------------------------------------------
// Kernel 0: fp32 -> bf16 cast of x and Wqkv.
// ---------------------------------------------------------------------------
__global__ __launch_bounds__(256) void cast_bf16(const float* __restrict__ x,
                                                 const float* __restrict__ w,
                                                 u16* __restrict__ xb,
                                                 u16* __restrict__ wb) {
    const size_t NX = 16777216 / 8, NW = 786432 / 8;
    size_t i = (size_t)blockIdx.x * 256 + threadIdx.x;
    const float* src; u16* dst; size_t e;
    if (i < NX)            { src = x; dst = xb; e = i; }
    else if (i < NX + NW)  { src = w; dst = wb; e = i - NX; }
    else return;
    const float4 a = *(const float4*)&src[e * 8];
    const float4 b = *(const float4*)&src[e * 8 + 4];
    u16 o[8] = { f2bf(a.x), f2bf(a.y), f2bf(a.z), f2bf(a.w),
                 f2bf(b.x), f2bf(b.y), f2bf(b.z), f2bf(b.w) };
    *(uint4*)&dst[e * 8] = *(const uint4*)o;
}

// ---------------------------------------------------------------------------
// Kernel 1: QKV projection, bf16 MFMA, fragment-major epilogue.
// Block 128m x 256f, BK=32, 4 waves, wave = 64m x 128f.
// ---------------------------------------------------------------------------
__global__ __launch_bounds__(256, 2) void qkv_gemm(const u16* __restrict__ xb,
                                                   const u16* __restrict__ wb,
                                                   const float* __restrict__ bias,
                                                   u16* __restrict__ qb,
                                                   u16* __restrict__ kb,
                                                   u16* __restrict__ vb) {
    __shared__ __align__(16) u16 sA[8 * 512];    // 8 m-tiles (also epilogue patch)
    __shared__ __align__(16) u16 sB[16 * 512];   // 16 f-tiles
    const int tid = threadIdx.x, lane = tid & 63, w = tid >> 6;
    const int lr = lane & 15, lh = lane >> 4;
    const int f0 = blockIdx.x * 256, m0 = blockIdx.y * 128;
    const int wm = w & 1, wf = w >> 1;

    f32x4 acc[4][8];
#pragma unroll
    for (int i = 0; i < 4; ++i)
#pragma unroll
        for (int j = 0; j < 8; ++j) acc[i][j] = (f32x4){0.f, 0.f, 0.f, 0.f};

#pragma unroll 1
    for (int k0 = 0; k0 < 512; k0 += 32) {
#pragma unroll
        for (int i = 0; i < 6; ++i) {            // 24 staging jobs, 6 per wave
            const int j = w * 6 + i;
            if (j < 8) {
                gload16(xb + (size_t)(m0 + j * 16 + lr) * 512 + k0 + lh * 8,
                        &sA[j * 512]);
            } else {
                const int jb = j - 8;
                gload16(wb + (size_t)(f0 + jb * 16 + lr) * 512 + k0 + lh * 8,
                        &sB[jb * 512]);
            }
        }
        __syncthreads();
        bf16x8 af[4], bf[8];
#pragma unroll
        for (int mt = 0; mt < 4; ++mt)
            af[mt] = *(const bf16x8*)&sA[(wm * 4 + mt) * 512 + lane * 8];
#pragma unroll
        for (int ft = 0; ft < 8; ++ft)
            bf[ft] = *(const bf16x8*)&sB[(wf * 8 + ft) * 512 + lane * 8];
#pragma unroll
        for (int mt = 0; mt < 4; ++mt)
#pragma unroll
            for (int ft = 0; ft < 8; ++ft)
                acc[mt][ft] = mfma16(af[mt], bf[ft], acc[mt][ft]);
        __syncthreads();
    }

    // ---- Epilogue: LDS bounce C-layout -> fragment-major, 16B stores ----
    u16* patch = &sA[w * 1024];     // 2 KB per wave; patch row stride 40 u16
    const int bdq = m0 >> 8;
    float bv[8];
#pragma unroll
    for (int ft = 0; ft < 8; ++ft) bv[ft] = bias[f0 + wf * 128 + ft * 16 + lr];

    if (f0 < 1024) {
        u16* dstb = (f0 < 512) ? qb : kb;
        const int mtileg = ((m0 & 255) >> 4) + wm * 4;
        const int kbase = ((f0 & 511) + wf * 128) >> 5;
#pragma unroll
        for (int mt = 0; mt < 4; ++mt)
#pragma unroll
            for (int ftp = 0; ftp < 4; ++ftp) {
#pragma unroll
                for (int h = 0; h < 2; ++h) {
                    const int ft = ftp * 2 + h;
                    const f32x4 a = acc[mt][ft];
#pragma unroll
                    for (int r = 0; r < 4; ++r)
                        patch[(lh * 4 + r) * 40 + h * 16 + lr] = f2bf(a[r] + bv[ft]);
                }
                asm volatile("s_waitcnt lgkmcnt(0)" ::: "memory");
                bf16x8 frag = *(const bf16x8*)&patch[lr * 40 + lh * 8];
                u16* dst = dstb +
                    ((size_t)(bdq * 16 + mtileg + mt) * 16 + (kbase + ftp)) * 512 +
                    lane * 8;
                *(bf16x8*)dst = frag;
            }
    } else {
        const int nbase = ((f0 - 1024) >> 4) + wf * 8;
        const int tbase = ((m0 & 255) >> 5) + wm * 2;
#pragma unroll
        for (int ft = 0; ft < 8; ++ft)
#pragma unroll
            for (int mtp = 0; mtp < 2; ++mtp) {
#pragma unroll
                for (int h = 0; h < 2; ++h) {
                    const f32x4 a = acc[mtp * 2 + h][ft];
#pragma unroll
                    for (int r = 0; r < 4; ++r)
                        patch[lr * 40 + h * 16 + lh * 4 + r] = f2bf(a[r] + bv[ft]);
                }
                asm volatile("s_waitcnt lgkmcnt(0)" ::: "memory");
                bf16x8 frag = *(const bf16x8*)&patch[lr * 40 + lh * 8];
                u16* dst = vb +
                    ((size_t)(bdq * 32 + nbase + ft) * 8 + (tbase + mtp)) * 512 +
                    lane * 8;
                *(bf16x8*)dst = frag;
            }
    }
}

// ---------------------------------------------------------------------------
// Kernel 2: attention. Block = (64 q-rows, bd), grid (4,128) = 2 blocks/CU.
// Zero-fill of outmat rows interleaved into phase-1 k-steps.
// ---------------------------------------------------------------------------
__global__ __launch_bounds__(256, 2) void attn_kernel(const u16* __restrict__ qb,
                                                      const u16* __restrict__ kb,
                                                      const u16* __restrict__ vb,
                                                      const int* __restrict__ n_ptr,
                                                      float* __restrict__ out,
                                                      float* __restrict__ outmat) {
    __shared__ __align__(16) u16 sQ[4 * 512];       // 4 KB
    __shared__ __align__(16) u16 sK[16 * 512];      // 16 KB (reused for V)
    __shared__ __align__(16) u16 sP[8 * 4 * 512];   // 32 KB frag-major P
    __shared__ float sStat[64][2];

    const int tid = threadIdx.x, lane = tid & 63, w = tid >> 6;
    const int lr = lane & 15, lh = lane >> 4;
    const int r0 = blockIdx.x * 64, bd = blockIdx.y;
    const int n = *n_ptr;
    const int wm = w & 1, wt = w >> 1;
    const int b_ = bd >> 3, dd = bd & 7;
    float* zbase = &outmat[(size_t)b_ * 4194304 + (size_t)(dd * 256 + r0) * 2048];
    const float4 f4z = make_float4(0.f, 0.f, 0.f, 0.f);

    f32x4 acc[2][8];
#pragma unroll
    for (int i = 0; i < 2; ++i)
#pragma unroll
        for (int j = 0; j < 8; ++j) acc[i][j] = (f32x4){0.f, 0.f, 0.f, 0.f};

    // ---------------- Phase 1: scores = Q K^T ----------------
#pragma unroll 1
    for (int k0 = 0; k0 < 512; k0 += 32) {
        const int kc = k0 >> 5;
#pragma unroll
        for (int i = 0; i < 5; ++i) {            // 4 Q + 16 K tiles, 5 per wave
            const int j = w * 5 + i;
            if (j < 4) {
                gload16(qb + ((size_t)(bd * 16 + blockIdx.x * 4 + j) * 16 + kc) * 512 +
                        lane * 8, &sQ[j * 512]);
            } else {
                const int jb = j - 4;
                gload16(kb + ((size_t)(bd * 16 + jb) * 16 + kc) * 512 + lane * 8,
                        &sK[jb * 512]);
            }
        }
        // interleaved zero-fill: 8 float4 stores per thread per k-step
#pragma unroll
        for (int u = 0; u < 8; ++u) {
            const int idx = (kc * 8 + u) * 256 + tid;   // covers 64*512 slots
            const int row = idx >> 9, c4 = idx & 511;
            if ((c4 >> 6) != dd)
                *(float4*)&zbase[(size_t)row * 2048 + c4 * 4] = f4z;
        }
        __syncthreads();
        bf16x8 af[2], bf[8];
#pragma unroll
        for (int mt = 0; mt < 2; ++mt)
            af[mt] = *(const bf16x8*)&sQ[(wm * 2 + mt) * 512 + lane * 8];
#pragma unroll
        for (int jt = 0; jt < 8; ++jt)
            bf[jt] = *(const bf16x8*)&sK[(wt * 8 + jt) * 512 + lane * 8];
#pragma unroll
        for (int mt = 0; mt < 2; ++mt)
#pragma unroll
            for (int jt = 0; jt < 8; ++jt)
                acc[mt][jt] = mfma16(af[mt], bf[jt], acc[mt][jt]);
        __syncthreads();
    }

    // ---------------- Phase 2: softmax + mask ----------------
    const float scale = 0.044194173824159216f;
#pragma unroll
    for (int i = 0; i < 2; ++i)
#pragma unroll
        for (int j = 0; j < 8; ++j) acc[i][j] *= scale;

    float rmax[2][4], rinv[2][4];
#pragma unroll
    for (int i = 0; i < 2; ++i)
#pragma unroll
        for (int r = 0; r < 4; ++r) {
            float v = -1e30f;
#pragma unroll
            for (int j = 0; j < 8; ++j) v = fmaxf(v, acc[i][j][r]);
            v = fmaxf(v, __shfl_xor(v, 1));
            v = fmaxf(v, __shfl_xor(v, 2));
            v = fmaxf(v, __shfl_xor(v, 4));
            v = fmaxf(v, __shfl_xor(v, 8));
            if (lr == 0) sStat[wm * 32 + i * 16 + lh * 4 + r][wt] = v;
        }
    __syncthreads();
#pragma unroll
    for (int i = 0; i < 2; ++i)
#pragma unroll
        for (int r = 0; r < 4; ++r) {
            const int m = wm * 32 + i * 16 + lh * 4 + r;
            rmax[i][r] = fmaxf(sStat[m][0], sStat[m][1]);
        }
    __syncthreads();
#pragma unroll
    for (int i = 0; i < 2; ++i)
#pragma unroll
        for (int r = 0; r < 4; ++r) {
            float s = 0.f;
#pragma unroll
            for (int j = 0; j < 8; ++j) {
                const float p = __expf(acc[i][j][r] - rmax[i][r]);
                acc[i][j][r] = p;
                s += p;
            }
            s += __shfl_xor(s, 1);
            s += __shfl_xor(s, 2);
            s += __shfl_xor(s, 4);
            s += __shfl_xor(s, 8);
            if (lr == 0) sStat[wm * 32 + i * 16 + lh * 4 + r][wt] = s;
        }
    __syncthreads();
#pragma unroll
    for (int i = 0; i < 2; ++i)
#pragma unroll
        for (int r = 0; r < 4; ++r) {
            const int m = wm * 32 + i * 16 + lh * 4 + r;
            rinv[i][r] = 1.0f / (sStat[m][0] + sStat[m][1]);
        }

#pragma unroll
    for (int i = 0; i < 2; ++i)
#pragma unroll
        for (int r = 0; r < 4; ++r) {
            const int m_loc = wm * 32 + i * 16 + lh * 4 + r;
            const int ig = r0 + m_loc;
            float* orow = &outmat[(size_t)b_ * 4194304 +
                                  (size_t)(dd * 256 + ig) * 2048 + dd * 256];
#pragma unroll
            for (int j = 0; j < 8; ++j) {
                const int t = wt * 128 + j * 16 + lr;
                float a = acc[i][j][r] * rinv[i][r];
                const int d = (ig > t) ? (ig - t) : (t - ig);
                int ov = 512 - d * n; if (ov < 0) ov = 0;
                if (d == 0 || ((2 * ov >= 512) && (ov < 512))) a = 0.f;
                orow[t] = a;
                // sP frag-major: tchunk=t>>5, mtile=m_loc>>4
                sP[((t >> 5) * 4 + (m_loc >> 4)) * 512 +
                   (((t & 31) >> 3) * 16 + (m_loc & 15)) * 8 + (t & 7)] = f2bf(a);
            }
        }
    __syncthreads();

    // ---------------- Phase 3: out = P V ----------------
#pragma unroll 1
    for (int nc = 0; nc < 2; ++nc) {
#pragma unroll
        for (int i = 0; i < 2; ++i)
#pragma unroll
            for (int j = 0; j < 8; ++j) acc[i][j] = (f32x4){0.f, 0.f, 0.f, 0.f};
#pragma unroll 1
        for (int t0 = 0; t0 < 256; t0 += 32) {
            const int tc = t0 >> 5;
#pragma unroll
            for (int i = 0; i < 4; ++i) {        // 16 V tiles, 4 per wave
                const int nt = w * 4 + i;
                gload16(vb + ((size_t)(bd * 32 + nc * 16 + nt) * 8 + tc) * 512 +
                        lane * 8, &sK[nt * 512]);
            }
            __syncthreads();
            bf16x8 af[2], bf[8];
#pragma unroll
            for (int mt = 0; mt < 2; ++mt)
                af[mt] = *(const bf16x8*)&sP[(tc * 4 + wm * 2 + mt) * 512 + lane * 8];
#pragma unroll
            for (int jt = 0; jt < 8; ++jt)
                bf[jt] = *(const bf16x8*)&sK[(wt * 8 + jt) * 512 + lane * 8];
#pragma unroll
            for (int mt = 0; mt < 2; ++mt)
#pragma unroll
                for (int jt = 0; jt < 8; ++jt)
                    acc[mt][jt] = mfma16(af[mt], bf[jt], acc[mt][jt]);
            __syncthreads();
        }
#pragma unroll
        for (int mt = 0; mt < 2; ++mt)
#pragma unroll
            for (int jt = 0; jt < 8; ++jt) {
                const int ng = nc * 256 + wt * 128 + jt * 16 + lr;
#pragma unroll
                for (int r = 0; r < 4; ++r) {
                    const int m_loc = wm * 32 + mt * 16 + lh * 4 + r;
                    out[((size_t)bd * 256 + r0 + m_loc) * 512 + ng] = acc[mt][jt][r];
                }
            }
    }
}

// ---------------------------------------------------------------------------
extern "C" void kernel_launch(void* const* d_in, const int* in_sizes, int n_in,
                              void* d_out, int out_size, void* d_ws, size_t ws_size,
                              hipStream_t stream) {
    (void)in_sizes; (void)n_in; (void)out_size; (void)ws_size;
    const float* x     = (const float*)d_in[0];
    const float* Wqkv  = (const float*)d_in[1];
    const float* bqkv  = (const float*)d_in[2];
    const int*   n_ptr = (const int*)d_in[3];

    float* out    = (float*)d_out;
    float* outmat = out + (size_t)16 * 2048 * 512;

    u16* xb = (u16*)d_ws;                 // 16,777,216
    u16* wb = xb + 16777216;              //    786,432
    u16* qb = wb + 786432;                // 16,777,216
    u16* kb = qb + 16777216;              // 16,777,216
    u16* vb = kb + 16777216;              // 16,777,216

    cast_bf16<<<8576, 256, 0, stream>>>(x, Wqkv, xb, wb);

    dim3 g1(6, 256);
    qkv_gemm<<<g1, 256, 0, stream>>>(xb, wb, bqkv, qb, kb, vb);

    dim3 g2(4, 128);                      // 64-row q-tiles, bd
    attn_kernel<<<g2, 256, 0, stream>>>(qb, kb, vb, n_ptr, out, outmat);
}